// Round 3
// baseline (133.601 us; speedup 1.0000x reference)
//
#include <hip/hip_runtime.h>
#include <math.h>

#define SEQ     1024
#define NBATCH  32
#define NC      256   // num_concept
#define NI      512   // 2*num_concept (inter values)
#define DIM     64
#define JT      64    // j-tile width (one lane per j)
#define NJT     (SEQ / JT)

// -------------------------------------------------------------------------
// Kernel 1: collapse the two einsums into a 512x256 lookup table.
//   tab[x*NC + y] = ( dot(alpha_inter[x], alpha_concept[y]),
//                     clip(dot(beta_inter[x], beta_concept[y]) + 1, 0, 10) )
// Clip is folded here so the O(B*S^2) loop never does it.
// One block per inter index x; one thread per concept y.
// -------------------------------------------------------------------------
__global__ __launch_bounds__(256) void build_tables(
    const float* __restrict__ aI, const float* __restrict__ aC,
    const float* __restrict__ bI, const float* __restrict__ bC,
    float2* __restrict__ tab)
{
    __shared__ float sA[DIM];
    __shared__ float sB[DIM];
    const int x = blockIdx.x;
    const int t = threadIdx.x;
    if (t < DIM)            sA[t]        = aI[x * DIM + t];
    else if (t < 2 * DIM)   sB[t - DIM]  = bI[x * DIM + (t - DIM)];
    __syncthreads();

    const int y = t;  // 256 threads == NC concepts
    const float4* ca = (const float4*)(aC + y * DIM);
    const float4* cb = (const float4*)(bC + y * DIM);
    float da = 0.f, db = 0.f;
#pragma unroll
    for (int k = 0; k < DIM / 4; ++k) {
        float4 va = ca[k];
        float4 vb = cb[k];
        da += sA[4*k+0]*va.x + sA[4*k+1]*va.y + sA[4*k+2]*va.z + sA[4*k+3]*va.w;
        db += sB[4*k+0]*vb.x + sB[4*k+1]*vb.y + sB[4*k+2]*vb.z + sB[4*k+3]*vb.w;
    }
    float beta = fminf(fmaxf(db + 1.0f, 0.0f), 10.0f);
    tab[x * NC + y] = make_float2(da, beta);
}

// -------------------------------------------------------------------------
// Kernel 2: causal cross-effect sum + fused epilogue.
//   sum_t[b,j] = sum_{i<j} A[inter_i, c_j] * exp(-B[inter_i, c_j] * L_ij)
//     with L_ij = ln(|t_i - t_j| + 1e-10) / ln(5)
//   out[b,j-1] = sigmoid(qbias[q_j] + cbias[c_j] + sum_t)      (j >= 1)
// Base-2 identity: exp(-beta*L) = exp2(-beta * log2(dt+eps) / ln(5)).
//   (log2(dt)·ln2/ln5 is the natural exponent; ×log2(e) cancels ln2 →
//    divide log2(dt) by ln5, NOT by log2(5). Round-2 bug was this constant.)
// Grid: (NBATCH, NJT). Block: 256 threads = 4 waves.
//   lane l owns column j = jt*64 + l; the 4 waves stride-split the i-range.
// -------------------------------------------------------------------------
__global__ __launch_bounds__(256) void hawkes_main(
    const int* __restrict__ concept_seq, const int* __restrict__ question_seq,
    const int* __restrict__ correct_seq, const int* __restrict__ time_seq,
    const float2* __restrict__ tab,
    const float* __restrict__ qbias, const float* __restrict__ cbias,
    float* __restrict__ out)
{
    __shared__ int   inter_s[SEQ];
    __shared__ float t_s[SEQ];
    __shared__ float part[4][JT];

    const int b   = blockIdx.x;
    const int jt  = blockIdx.y;
    const int tid = threadIdx.x;
    const int w   = tid >> 6;   // wave id 0..3
    const int l   = tid & 63;   // lane

    const int I = (jt + 1) * JT;  // need sources i in [0, I)

    // Stage this batch's prefix of inter indices + times into LDS.
    for (int idx = tid; idx < I; idx += 256) {
        int c = concept_seq[b * SEQ + idx];
        inter_s[idx] = c + NC * correct_seq[b * SEQ + idx];
        t_s[idx]     = (float)time_seq[b * SEQ + idx];
    }
    __syncthreads();

    const int   j  = jt * JT + l;
    const int   cj = concept_seq[b * SEQ + j];
    const float tj = t_s[j];

    const float inv_ln5 = 0.6213349345596119f;  // 1/ln(5)
    float acc = 0.0f;

    // Waves stride-split the i loop; i is wave-uniform -> inter_s[i]/t_s[i]
    // are LDS broadcasts and the table row base is wave-uniform.
    for (int i = w; i < I; i += 4) {
        const int   s  = inter_s[i];
        const float ti = t_s[i];
        float2 ab = tab[s * NC + cj];            // (alpha, clipped beta)
        float dt  = fabsf(tj - ti);
        float dl  = __builtin_amdgcn_logf(dt + 1e-10f) * inv_ln5;  // log2(dt)/ln5
        float e   = __builtin_amdgcn_exp2f(-ab.y * dl);
        float v   = ab.x * e;
        // select, NOT multiply-by-mask: masked lanes may hold inf (dt==0
        // diagonal with large beta) and 0*inf would poison the accumulator.
        acc += (i < j) ? v : 0.0f;
    }

    part[w][l] = acc;
    __syncthreads();

    if (w == 0) {
        float s = part[0][l] + part[1][l] + part[2][l] + part[3][l];
        if (j >= 1) {
            float z = qbias[question_seq[b * SEQ + j]] + cbias[cj] + s;
            // sigmoid(z) = 1/(1+exp(-z)); exp(-z)=exp2(-z*log2(e))
            float ez = __builtin_amdgcn_exp2f(-z * 1.4426950408889634f);
            out[b * (SEQ - 1) + (j - 1)] = 1.0f / (1.0f + ez);
        }
    }
}

// -------------------------------------------------------------------------
extern "C" void kernel_launch(void* const* d_in, const int* in_sizes, int n_in,
                              void* d_out, int out_size, void* d_ws, size_t ws_size,
                              hipStream_t stream) {
    const int*   concept_seq  = (const int*)  d_in[0];
    const int*   question_seq = (const int*)  d_in[1];
    const int*   correct_seq  = (const int*)  d_in[2];
    const int*   time_seq     = (const int*)  d_in[3];
    const float* aI           = (const float*)d_in[4];
    const float* aC           = (const float*)d_in[5];
    const float* bI           = (const float*)d_in[6];
    const float* bC           = (const float*)d_in[7];
    const float* qbias        = (const float*)d_in[8];
    const float* cbias        = (const float*)d_in[9];
    float*       out          = (float*)d_out;

    float2* tab = (float2*)d_ws;  // NI*NC float2 = 1 MiB

    build_tables<<<NI, 256, 0, stream>>>(aI, aC, bI, bC, tab);
    hawkes_main<<<dim3(NBATCH, NJT), 256, 0, stream>>>(
        concept_seq, question_seq, correct_seq, time_seq, tab, qbias, cbias, out);
}

// Round 4
// 103.763 us; speedup vs baseline: 1.2876x; 1.2876x over previous
//
#include <hip/hip_runtime.h>
#include <math.h>

#define SEQ     1024
#define NBATCH  32
#define NC      256   // num_concept
#define NI      512   // 2*num_concept (inter values)
#define DIM     64
#define JT      64    // j-tile width (one lane per j)
#define NJT     (SEQ / JT)   // 16
#define NWAVE   16           // waves per block (1024 threads)

// -------------------------------------------------------------------------
// Kernel 1: collapse the two einsums into a 512x256 lookup table.
//   tab[x*NC + y] = ( dot(alpha_inter[x], alpha_concept[y]),
//                     clip(dot(beta_inter[x], beta_concept[y]) + 1, 0, 10) )
// -------------------------------------------------------------------------
__global__ __launch_bounds__(256) void build_tables(
    const float* __restrict__ aI, const float* __restrict__ aC,
    const float* __restrict__ bI, const float* __restrict__ bC,
    float2* __restrict__ tab)
{
    __shared__ float sA[DIM];
    __shared__ float sB[DIM];
    const int x = blockIdx.x;
    const int t = threadIdx.x;
    if (t < DIM)            sA[t]        = aI[x * DIM + t];
    else if (t < 2 * DIM)   sB[t - DIM]  = bI[x * DIM + (t - DIM)];
    __syncthreads();

    const int y = t;  // 256 threads == NC concepts
    const float4* ca = (const float4*)(aC + y * DIM);
    const float4* cb = (const float4*)(bC + y * DIM);
    float da = 0.f, db = 0.f;
#pragma unroll
    for (int k = 0; k < DIM / 4; ++k) {
        float4 va = ca[k];
        float4 vb = cb[k];
        da += sA[4*k+0]*va.x + sA[4*k+1]*va.y + sA[4*k+2]*va.z + sA[4*k+3]*va.w;
        db += sB[4*k+0]*vb.x + sB[4*k+1]*vb.y + sB[4*k+2]*vb.z + sB[4*k+3]*vb.w;
    }
    float beta = fminf(fmaxf(db + 1.0f, 0.0f), 10.0f);
    tab[x * NC + y] = make_float2(da, beta);
}

// -------------------------------------------------------------------------
// Kernel 2: causal cross-effect sum + fused epilogue.
//   sum_t[b,j] = sum_{i<j} A[inter_i, c_j] * exp(-B[inter_i, c_j] * L_ij)
//     L_ij = ln(|t_i - t_j| + 1e-10)/ln5;  exp2 form: -beta*log2(dt)/ln5.
//   out[b,j-1] = sigmoid(qbias[q_j] + cbias[c_j] + sum_t)   (j >= 1)
//
// Round-4 restructure (was: 512 blocks x 4 waves, 16x work imbalance,
// 500 cyc/iter serial chain, VALUBusy 13.6%):
//   grid (NBATCH, NJT/2) = 256 blocks x 1024 thr (16 waves). Block (b,p)
//   handles PAIRED j-tiles {15-p, p} -> every block does exactly 17*64
//   source-rows: perfect balance. Waves take contiguous I/16 i-chunks;
//   unroll 4 keeps 4 independent table-gathers in flight.
// -------------------------------------------------------------------------
__global__ __launch_bounds__(1024) void hawkes_main(
    const int* __restrict__ concept_seq, const int* __restrict__ question_seq,
    const int* __restrict__ correct_seq, const int* __restrict__ time_seq,
    const float2* __restrict__ tab,
    const float* __restrict__ qbias, const float* __restrict__ cbias,
    float* __restrict__ out)
{
    __shared__ int   inter_s[SEQ];
    __shared__ float t_s[SEQ];
    __shared__ float part[NWAVE][JT];

    const int b   = blockIdx.x;
    const int p   = blockIdx.y;          // pair id 0..7
    const int tid = threadIdx.x;
    const int w   = tid >> 6;            // wave id 0..15
    const int l   = tid & 63;            // lane

    const int jt_big   = (NJT - 1) - p;  // 15-p  (larger tile)
    const int jt_small = p;
    const int I_big    = (jt_big + 1) * JT;   // covers both tiles' prefixes

    // Stage this batch's prefix of inter indices + times into LDS (once).
    for (int idx = tid; idx < I_big; idx += 1024) {
        int c = concept_seq[b * SEQ + idx];
        inter_s[idx] = c + NC * correct_seq[b * SEQ + idx];
        t_s[idx]     = (float)time_seq[b * SEQ + idx];
    }
    __syncthreads();

    const float inv_ln5 = 0.6213349345596119f;  // 1/ln(5)

#pragma unroll
    for (int tile = 0; tile < 2; ++tile) {
        const int jt = tile ? jt_small : jt_big;
        const int I  = (jt + 1) * JT;
        const int j  = jt * JT + l;
        const int cj = concept_seq[b * SEQ + j];
        const float tj = t_s[j];

        float acc = 0.0f;
        const int chunk = I >> 4;        // I/16; I multiple of 64 -> >=4
        const int i0 = w * chunk;
#pragma unroll 4
        for (int i = i0; i < i0 + chunk; ++i) {
            const int   s  = inter_s[i];
            const float ti = t_s[i];
            float2 ab = tab[s * NC + cj];       // (alpha, clipped beta)
            float dt  = fabsf(tj - ti);
            float dl  = __builtin_amdgcn_logf(dt + 1e-10f) * inv_ln5;
            float e   = __builtin_amdgcn_exp2f(-ab.y * dl);
            // select, NOT multiply-by-mask: masked lanes may hold inf
            // (dt==0 with large beta) and 0*inf would poison the sum.
            acc += (i < j) ? ab.x * e : 0.0f;
        }

        __syncthreads();                 // (t>0: previous epilogue done reading)
        part[w][l] = acc;
        __syncthreads();

        if (w == 0) {
            float s = 0.0f;
#pragma unroll
            for (int k = 0; k < NWAVE; ++k) s += part[k][l];
            if (j >= 1) {
                float z = qbias[question_seq[b * SEQ + j]] + cbias[cj] + s;
                float ez = __builtin_amdgcn_exp2f(-z * 1.4426950408889634f);
                out[b * (SEQ - 1) + (j - 1)] = 1.0f / (1.0f + ez);
            }
        }
    }
}

// -------------------------------------------------------------------------
extern "C" void kernel_launch(void* const* d_in, const int* in_sizes, int n_in,
                              void* d_out, int out_size, void* d_ws, size_t ws_size,
                              hipStream_t stream) {
    const int*   concept_seq  = (const int*)  d_in[0];
    const int*   question_seq = (const int*)  d_in[1];
    const int*   correct_seq  = (const int*)  d_in[2];
    const int*   time_seq     = (const int*)  d_in[3];
    const float* aI           = (const float*)d_in[4];
    const float* aC           = (const float*)d_in[5];
    const float* bI           = (const float*)d_in[6];
    const float* bC           = (const float*)d_in[7];
    const float* qbias        = (const float*)d_in[8];
    const float* cbias        = (const float*)d_in[9];
    float*       out          = (float*)d_out;

    float2* tab = (float2*)d_ws;  // NI*NC float2 = 1 MiB

    build_tables<<<NI, 256, 0, stream>>>(aI, aC, bI, bC, tab);
    hawkes_main<<<dim3(NBATCH, NJT / 2), 1024, 0, stream>>>(
        concept_seq, question_seq, correct_seq, time_seq, tab, qbias, cbias, out);
}